// Round 1
// baseline (1352.322 us; speedup 1.0000x reference)
//
#include <hip/hip_runtime.h>

#define N_NODES 100000
#define N_EDGES 3200000
#define IN_DIM 32
#define HID 64

// ---------------------------------------------------------------------------
// K1: fused degree-count + scatter-add of x[src] into agg1[dst].
// 32 lanes per edge -> each neighbor row is one coalesced 128B read.
// ---------------------------------------------------------------------------
__global__ __launch_bounds__(256) void scatter1(
    const int* __restrict__ src, const int* __restrict__ dst,
    const float* __restrict__ x, float* __restrict__ agg1,
    float* __restrict__ cnt) {
  long long t = (long long)blockIdx.x * blockDim.x + threadIdx.x;
  int e = (int)(t >> 5);
  int f = (int)(t & 31);
  if (e >= N_EDGES) return;
  int s = src[e];
  int d = dst[e];
  float v = x[(long long)s * IN_DIM + f];
  atomicAdd(&agg1[(long long)d * IN_DIM + f], v);
  if (f == 0) atomicAdd(&cnt[d], 1.0f);
}

// ---------------------------------------------------------------------------
// K2: h1 = relu(mean1 @ w1_l^T + b1_l + x @ w1_r^T)
// 4 nodes per block (1 wave each); weights staged in LDS with +1 pad.
// ---------------------------------------------------------------------------
__global__ __launch_bounds__(256) void linear1(
    const float* __restrict__ x, const float* __restrict__ agg1,
    const float* __restrict__ cnt, const float* __restrict__ w_l,
    const float* __restrict__ b_l, const float* __restrict__ w_r,
    float* __restrict__ h1) {
  __shared__ float s_wl[HID * 33];   // padded [64][33]
  __shared__ float s_wr[HID * 33];
  __shared__ float s_mean[4][IN_DIM];
  __shared__ float s_x[4][IN_DIM];

  int tid = threadIdx.x;
  for (int idx = tid; idx < HID * IN_DIM; idx += 256) {
    int j = idx >> 5, f = idx & 31;
    s_wl[j * 33 + f] = w_l[idx];
    s_wr[j * 33 + f] = w_r[idx];
  }

  int w = tid >> 6;            // wave id -> node within block
  int lane = tid & 63;
  int node = blockIdx.x * 4 + w;   // grid is exact: 100000/4 blocks

  if (lane < IN_DIM) {
    float c = cnt[node];
    float rinv = 1.0f / fmaxf(c, 1.0f);
    s_mean[w][lane] = agg1[node * IN_DIM + lane] * rinv;
  } else {
    int f = lane - IN_DIM;
    s_x[w][f] = x[node * IN_DIM + f];
  }
  __syncthreads();

  int j = lane;                // output channel 0..63
  float acc = b_l[j];
#pragma unroll
  for (int f = 0; f < IN_DIM; ++f) {
    acc += s_mean[w][f] * s_wl[j * 33 + f] + s_x[w][f] * s_wr[j * 33 + f];
  }
  h1[node * HID + j] = fmaxf(acc, 0.0f);
}

// ---------------------------------------------------------------------------
// K3: scatter-add h1[src] into agg2[dst]. 64 lanes per edge (256B coalesced).
// ---------------------------------------------------------------------------
__global__ __launch_bounds__(256) void scatter2(
    const int* __restrict__ src, const int* __restrict__ dst,
    const float* __restrict__ h1, float* __restrict__ agg2) {
  long long t = (long long)blockIdx.x * blockDim.x + threadIdx.x;
  int e = (int)(t >> 6);
  int f = (int)(t & 63);
  if (e >= N_EDGES) return;
  int s = src[e];
  int d = dst[e];
  float v = h1[(long long)s * HID + f];
  atomicAdd(&agg2[(long long)d * HID + f], v);
}

// ---------------------------------------------------------------------------
// K4: h2 = relu(mean2 @ w2_l^T + b2_l + h1 @ w2_r^T); out = h2 @ w_cls^T + b_cls
// 4 nodes per block (1 wave each); fused classifier with 64-lane reduction.
// ---------------------------------------------------------------------------
__global__ __launch_bounds__(256) void linear2_cls(
    const float* __restrict__ h1, const float* __restrict__ agg2,
    const float* __restrict__ cnt, const float* __restrict__ w_l,
    const float* __restrict__ b_l, const float* __restrict__ w_r,
    const float* __restrict__ wc, const float* __restrict__ bc,
    float* __restrict__ out) {
  __shared__ float s_wl[HID * 65];   // padded [64][65]
  __shared__ float s_wr[HID * 65];
  __shared__ float s_mean[4][HID];
  __shared__ float s_h[4][HID];
  __shared__ float s_wc[HID];

  int tid = threadIdx.x;
  for (int idx = tid; idx < HID * HID; idx += 256) {
    int j = idx >> 6, f = idx & 63;
    s_wl[j * 65 + f] = w_l[idx];
    s_wr[j * 65 + f] = w_r[idx];
  }
  if (tid < HID) s_wc[tid] = wc[tid];

  int w = tid >> 6;
  int lane = tid & 63;
  int node = blockIdx.x * 4 + w;   // exact grid

  float c = cnt[node];
  float rinv = 1.0f / fmaxf(c, 1.0f);
  s_mean[w][lane] = agg2[node * HID + lane] * rinv;
  s_h[w][lane] = h1[node * HID + lane];
  __syncthreads();

  int j = lane;
  float acc = b_l[j];
#pragma unroll
  for (int f = 0; f < HID; ++f) {
    acc += s_mean[w][f] * s_wl[j * 65 + f] + s_h[w][f] * s_wr[j * 65 + f];
  }
  float h2 = fmaxf(acc, 0.0f);
  float contrib = h2 * s_wc[j];
#pragma unroll
  for (int off = 32; off > 0; off >>= 1)
    contrib += __shfl_down(contrib, off, 64);
  if (lane == 0) out[node] = contrib + bc[0];
}

// ---------------------------------------------------------------------------
extern "C" void kernel_launch(void* const* d_in, const int* in_sizes, int n_in,
                              void* d_out, int out_size, void* d_ws, size_t ws_size,
                              hipStream_t stream) {
  const float* x   = (const float*)d_in[0];
  const int*   ei  = (const int*)d_in[1];
  const float* w1l = (const float*)d_in[2];
  const float* b1l = (const float*)d_in[3];
  const float* w1r = (const float*)d_in[4];
  const float* w2l = (const float*)d_in[5];
  const float* b2l = (const float*)d_in[6];
  const float* w2r = (const float*)d_in[7];
  const float* wc  = (const float*)d_in[8];
  const float* bc  = (const float*)d_in[9];
  float* out = (float*)d_out;

  const int* src = ei;             // edge_index[0]
  const int* dst = ei + N_EDGES;   // edge_index[1]

  // workspace layout (bytes), 256B-aligned slices
  char* ws = (char*)d_ws;
  float* agg1 = (float*)(ws + 0);           // N*32 f32 = 12.8 MB
  float* cnt  = (float*)(ws + 12800000);    // N f32    = 0.4 MB
  float* h1   = (float*)(ws + 13200128);    // N*64 f32 = 25.6 MB
  float* agg2 = (float*)(ws + 38800128);    // N*64 f32 = 25.6 MB
  // total: 64,400,128 bytes

  hipMemsetAsync(agg1, 0, (size_t)N_NODES * IN_DIM * sizeof(float), stream);
  hipMemsetAsync(cnt,  0, (size_t)N_NODES * sizeof(float), stream);
  hipMemsetAsync(agg2, 0, (size_t)N_NODES * HID * sizeof(float), stream);

  {
    long long T = (long long)N_EDGES * 32;
    int blocks = (int)((T + 255) / 256);
    scatter1<<<blocks, 256, 0, stream>>>(src, dst, x, agg1, cnt);
  }
  linear1<<<N_NODES / 4, 256, 0, stream>>>(x, agg1, cnt, w1l, b1l, w1r, h1);
  {
    long long T = (long long)N_EDGES * 64;
    int blocks = (int)((T + 255) / 256);
    scatter2<<<blocks, 256, 0, stream>>>(src, dst, h1, agg2);
  }
  linear2_cls<<<N_NODES / 4, 256, 0, stream>>>(h1, agg2, cnt, w2l, b2l, w2r,
                                               wc, bc, out);
}

// Round 2
// 859.622 us; speedup vs baseline: 1.5732x; 1.5732x over previous
//
#include <hip/hip_runtime.h>

#define N_NODES 100000
#define N_EDGES 3200000
#define IN_DIM 32
#define HID 64
#define SCAN_ELEMS 1024
#define N_SCAN_BLOCKS ((N_NODES + SCAN_ELEMS - 1) / SCAN_ELEMS)  // 98

// ---------------------------------------------------------------------------
// CSR build stage 1: histogram of dst (int atomics, L2-resident, no writeback
// storm like fp32 atomics).
// ---------------------------------------------------------------------------
__global__ __launch_bounds__(256) void hist_kernel(
    const int* __restrict__ dst, int* __restrict__ hist) {
  int e = blockIdx.x * 256 + threadIdx.x;
  if (e < N_EDGES) atomicAdd(&hist[dst[e]], 1);
}

// ---------------------------------------------------------------------------
// CSR stage 2a: per-block exclusive scan (1024 elems/block), block totals out.
// ---------------------------------------------------------------------------
__global__ __launch_bounds__(256) void scan_local(
    const int* __restrict__ hist, int* __restrict__ row_ptr,
    int* __restrict__ blk_sums) {
  __shared__ int s[256];
  int tid = threadIdx.x;
  int base = blockIdx.x * SCAN_ELEMS + tid * 4;
  int v[4];
  int tsum = 0;
#pragma unroll
  for (int i = 0; i < 4; ++i) {
    int g = base + i;
    v[i] = (g < N_NODES) ? hist[g] : 0;
    tsum += v[i];
  }
  s[tid] = tsum;
  __syncthreads();
  for (int off = 1; off < 256; off <<= 1) {
    int t = (tid >= off) ? s[tid - off] : 0;
    __syncthreads();
    s[tid] += t;
    __syncthreads();
  }
  int run = s[tid] - tsum;  // exclusive within block
#pragma unroll
  for (int i = 0; i < 4; ++i) {
    int g = base + i;
    if (g < N_NODES) row_ptr[g] = run;
    run += v[i];
  }
  if (tid == 255) blk_sums[blockIdx.x] = s[255];
}

// CSR stage 2b: exclusive scan of block totals (single block).
__global__ __launch_bounds__(128) void scan_blk(int* blk_sums) {
  __shared__ int s[128];
  int tid = threadIdx.x;
  int v = (tid < N_SCAN_BLOCKS) ? blk_sums[tid] : 0;
  s[tid] = v;
  __syncthreads();
  for (int off = 1; off < 128; off <<= 1) {
    int t = (tid >= off) ? s[tid - off] : 0;
    __syncthreads();
    s[tid] += t;
    __syncthreads();
  }
  if (tid < N_SCAN_BLOCKS) blk_sums[tid] = s[tid] - v;  // exclusive
}

// CSR stage 2c: add block offsets; write sentinel row_ptr[N] = E.
__global__ __launch_bounds__(256) void scan_add(
    int* __restrict__ row_ptr, const int* __restrict__ blk_sums) {
  int tid = threadIdx.x;
  int base = blockIdx.x * SCAN_ELEMS + tid * 4;
  int add = blk_sums[blockIdx.x];
#pragma unroll
  for (int i = 0; i < 4; ++i) {
    int g = base + i;
    if (g < N_NODES) row_ptr[g] += add;
  }
  if (blockIdx.x == 0 && tid == 0) row_ptr[N_NODES] = N_EDGES;
}

// ---------------------------------------------------------------------------
// CSR stage 3: bucket-fill sorted_src (src ids grouped by dst).
// ---------------------------------------------------------------------------
__global__ __launch_bounds__(256) void fill_kernel(
    const int* __restrict__ src, const int* __restrict__ dst,
    const int* __restrict__ row_ptr, int* __restrict__ cursor,
    int* __restrict__ sorted_src) {
  int e = blockIdx.x * 256 + threadIdx.x;
  if (e >= N_EDGES) return;
  int d = dst[e];
  int pos = atomicAdd(&cursor[d], 1);
  sorted_src[row_ptr[d] + pos] = src[e];
}

// ---------------------------------------------------------------------------
// Layer 1 fused: gather-mean over CSR + lin_l + lin_r + bias + relu.
// 1 wave per node, 4 nodes/block. Two edges in flight per iter (half-waves).
// ---------------------------------------------------------------------------
__global__ __launch_bounds__(256) void layer1_fused(
    const float* __restrict__ x, const int* __restrict__ row_ptr,
    const int* __restrict__ sorted_src, const float* __restrict__ w_l,
    const float* __restrict__ b_l, const float* __restrict__ w_r,
    float* __restrict__ h1) {
  __shared__ float s_wl[HID * 33];
  __shared__ float s_wr[HID * 33];
  __shared__ float s_mean[4][IN_DIM];
  __shared__ float s_x[4][IN_DIM];

  int tid = threadIdx.x;
  for (int idx = tid; idx < HID * IN_DIM; idx += 256) {
    int j = idx >> 5, f = idx & 31;
    s_wl[j * 33 + f] = w_l[idx];
    s_wr[j * 33 + f] = w_r[idx];
  }
  int w = tid >> 6, lane = tid & 63;
  int node = blockIdx.x * 4 + w;  // exact: 25000*4
  int f = lane & 31, half = lane >> 5;
  int rs = row_ptr[node], re = row_ptr[node + 1];
  int deg = re - rs;
  float acc = 0.f;
  for (int kk = half; kk < deg; kk += 2) {
    int sN = sorted_src[rs + kk];       // broadcast-ish L1 hit
    acc += x[sN * IN_DIM + f];          // 128B coalesced gather
  }
  acc += __shfl_xor(acc, 32, 64);       // combine the two halves
  float rinv = 1.0f / fmaxf((float)deg, 1.0f);
  if (half == 0)
    s_mean[w][f] = acc * rinv;
  else
    s_x[w][f] = x[node * IN_DIM + f];
  __syncthreads();

  int j = lane;
  float a2 = b_l[j];
#pragma unroll
  for (int ff = 0; ff < IN_DIM; ++ff)
    a2 += s_mean[w][ff] * s_wl[j * 33 + ff] + s_x[w][ff] * s_wr[j * 33 + ff];
  h1[node * HID + j] = fmaxf(a2, 0.0f);
}

// ---------------------------------------------------------------------------
// Layer 2 fused: gather-mean + lin_l + lin_r + relu + classifier dot.
// 1 wave per node; 2 accumulators for load ILP.
// ---------------------------------------------------------------------------
__global__ __launch_bounds__(256) void layer2_fused(
    const float* __restrict__ h1, const int* __restrict__ row_ptr,
    const int* __restrict__ sorted_src, const float* __restrict__ w_l,
    const float* __restrict__ b_l, const float* __restrict__ w_r,
    const float* __restrict__ wc, const float* __restrict__ bc,
    float* __restrict__ out) {
  __shared__ float s_wl[HID * 65];
  __shared__ float s_wr[HID * 65];
  __shared__ float s_mean[4][HID];
  __shared__ float s_h[4][HID];
  __shared__ float s_wc[HID];

  int tid = threadIdx.x;
  for (int idx = tid; idx < HID * HID; idx += 256) {
    int j = idx >> 6, f = idx & 63;
    s_wl[j * 65 + f] = w_l[idx];
    s_wr[j * 65 + f] = w_r[idx];
  }
  if (tid < HID) s_wc[tid] = wc[tid];

  int w = tid >> 6, lane = tid & 63;
  int node = blockIdx.x * 4 + w;
  int rs = row_ptr[node], re = row_ptr[node + 1];
  int deg = re - rs;
  float acc0 = 0.f, acc1 = 0.f;
  int kk = 0;
  for (; kk + 1 < deg; kk += 2) {
    int s0 = sorted_src[rs + kk];
    int s1 = sorted_src[rs + kk + 1];
    acc0 += h1[s0 * HID + lane];        // 256B coalesced gather
    acc1 += h1[s1 * HID + lane];
  }
  if (kk < deg) acc0 += h1[sorted_src[rs + kk] * HID + lane];
  float rinv = 1.0f / fmaxf((float)deg, 1.0f);
  s_mean[w][lane] = (acc0 + acc1) * rinv;
  s_h[w][lane] = h1[node * HID + lane];
  __syncthreads();

  int j = lane;
  float a2 = b_l[j];
#pragma unroll
  for (int ff = 0; ff < HID; ++ff)
    a2 += s_mean[w][ff] * s_wl[j * 65 + ff] + s_h[w][ff] * s_wr[j * 65 + ff];
  float h2 = fmaxf(a2, 0.f);
  float contrib = h2 * s_wc[j];
#pragma unroll
  for (int off = 32; off > 0; off >>= 1)
    contrib += __shfl_down(contrib, off, 64);
  if (lane == 0) out[node] = contrib + bc[0];
}

// ---------------------------------------------------------------------------
extern "C" void kernel_launch(void* const* d_in, const int* in_sizes, int n_in,
                              void* d_out, int out_size, void* d_ws, size_t ws_size,
                              hipStream_t stream) {
  const float* x   = (const float*)d_in[0];
  const int*   ei  = (const int*)d_in[1];
  const float* w1l = (const float*)d_in[2];
  const float* b1l = (const float*)d_in[3];
  const float* w1r = (const float*)d_in[4];
  const float* w2l = (const float*)d_in[5];
  const float* b2l = (const float*)d_in[6];
  const float* w2r = (const float*)d_in[7];
  const float* wc  = (const float*)d_in[8];
  const float* bc  = (const float*)d_in[9];
  float* out = (float*)d_out;

  const int* src = ei;             // edge_index[0]
  const int* dst = ei + N_EDGES;   // edge_index[1]

  // workspace layout (256B-aligned slices)
  char* ws = (char*)d_ws;
  int* row_ptr    = (int*)(ws + 0);          // (N+1)*4 = 400,004 B
  int* hist       = (int*)(ws + 400128);     // N*4     = 400,000 B (reused as cursor)
  int* blk_sums   = (int*)(ws + 800256);     // 512 B
  int* sorted_src = (int*)(ws + 800768);     // E*4     = 12.8 MB
  float* h1       = (float*)(ws + 13600768); // N*64*4  = 25.6 MB
  // total 39.2 MB

  hipMemsetAsync(hist, 0, (size_t)N_NODES * sizeof(int), stream);
  hist_kernel<<<(N_EDGES + 255) / 256, 256, 0, stream>>>(dst, hist);
  scan_local<<<N_SCAN_BLOCKS, 256, 0, stream>>>(hist, row_ptr, blk_sums);
  scan_blk<<<1, 128, 0, stream>>>(blk_sums);
  scan_add<<<N_SCAN_BLOCKS, 256, 0, stream>>>(row_ptr, blk_sums);
  hipMemsetAsync(hist, 0, (size_t)N_NODES * sizeof(int), stream);  // -> cursor
  fill_kernel<<<(N_EDGES + 255) / 256, 256, 0, stream>>>(src, dst, row_ptr,
                                                         hist, sorted_src);
  layer1_fused<<<N_NODES / 4, 256, 0, stream>>>(x, row_ptr, sorted_src,
                                                w1l, b1l, w1r, h1);
  layer2_fused<<<N_NODES / 4, 256, 0, stream>>>(h1, row_ptr, sorted_src,
                                                w2l, b2l, w2r, wc, bc, out);
}

// Round 3
// 591.476 us; speedup vs baseline: 2.2864x; 1.4533x over previous
//
#include <hip/hip_runtime.h>

#define N_NODES 100000
#define N_EDGES 3200000
#define IN_DIM 32
#define HID 64
#define SCAN_ELEMS 1024
#define N_SCAN_BLOCKS ((N_NODES + SCAN_ELEMS - 1) / SCAN_ELEMS)  // 98

typedef unsigned short bfraw;

__device__ __forceinline__ bfraw f2bf(float f) {
  unsigned u = __builtin_bit_cast(unsigned, f);
  unsigned r = (u + 0x7fffu + ((u >> 16) & 1u)) >> 16;  // RNE
  return (bfraw)r;
}
__device__ __forceinline__ float bf2f(bfraw u) {
  unsigned v = ((unsigned)u) << 16;
  return __builtin_bit_cast(float, v);
}

// ---------------------------------------------------------------------------
// prep: x (f32) -> xb (bf16)
// ---------------------------------------------------------------------------
__global__ __launch_bounds__(256) void to_bf16(
    const float* __restrict__ in, bfraw* __restrict__ outv, int n) {
  int i = blockIdx.x * 256 + threadIdx.x;
  if (i < n) outv[i] = f2bf(in[i]);
}

// ---------------------------------------------------------------------------
// CSR build stage 1: histogram of dst.
// ---------------------------------------------------------------------------
__global__ __launch_bounds__(256) void hist_kernel(
    const int* __restrict__ dst, int* __restrict__ hist) {
  int e = blockIdx.x * 256 + threadIdx.x;
  if (e < N_EDGES) atomicAdd(&hist[dst[e]], 1);
}

// CSR stage 2a: per-block exclusive scan (1024 elems/block).
__global__ __launch_bounds__(256) void scan_local(
    const int* __restrict__ hist, int* __restrict__ row_ptr,
    int* __restrict__ blk_sums) {
  __shared__ int s[256];
  int tid = threadIdx.x;
  int base = blockIdx.x * SCAN_ELEMS + tid * 4;
  int v[4];
  int tsum = 0;
#pragma unroll
  for (int i = 0; i < 4; ++i) {
    int g = base + i;
    v[i] = (g < N_NODES) ? hist[g] : 0;
    tsum += v[i];
  }
  s[tid] = tsum;
  __syncthreads();
  for (int off = 1; off < 256; off <<= 1) {
    int t = (tid >= off) ? s[tid - off] : 0;
    __syncthreads();
    s[tid] += t;
    __syncthreads();
  }
  int run = s[tid] - tsum;
#pragma unroll
  for (int i = 0; i < 4; ++i) {
    int g = base + i;
    if (g < N_NODES) row_ptr[g] = run;
    run += v[i];
  }
  if (tid == 255) blk_sums[blockIdx.x] = s[255];
}

__global__ __launch_bounds__(128) void scan_blk(int* blk_sums) {
  __shared__ int s[128];
  int tid = threadIdx.x;
  int v = (tid < N_SCAN_BLOCKS) ? blk_sums[tid] : 0;
  s[tid] = v;
  __syncthreads();
  for (int off = 1; off < 128; off <<= 1) {
    int t = (tid >= off) ? s[tid - off] : 0;
    __syncthreads();
    s[tid] += t;
    __syncthreads();
  }
  if (tid < N_SCAN_BLOCKS) blk_sums[tid] = s[tid] - v;
}

__global__ __launch_bounds__(256) void scan_add(
    int* __restrict__ row_ptr, const int* __restrict__ blk_sums) {
  int tid = threadIdx.x;
  int base = blockIdx.x * SCAN_ELEMS + tid * 4;
  int add = blk_sums[blockIdx.x];
#pragma unroll
  for (int i = 0; i < 4; ++i) {
    int g = base + i;
    if (g < N_NODES) row_ptr[g] += add;
  }
  if (blockIdx.x == 0 && tid == 0) row_ptr[N_NODES] = N_EDGES;
}

// CSR stage 3: bucket-fill (NT store: avoid write-allocate on random 4B).
__global__ __launch_bounds__(256) void fill_kernel(
    const int* __restrict__ src, const int* __restrict__ dst,
    const int* __restrict__ row_ptr, int* __restrict__ cursor,
    int* __restrict__ sorted_src) {
  int e = blockIdx.x * 256 + threadIdx.x;
  if (e >= N_EDGES) return;
  int d = dst[e];
  int pos = atomicAdd(&cursor[d], 1);
  __builtin_nontemporal_store(src[e], &sorted_src[row_ptr[d] + pos]);
}

// ---------------------------------------------------------------------------
// Layer 1 fused: gather-mean(bf16 x) + lin_l + lin_r + relu -> h1 (bf16).
// 4 quarter-wave groups/wave, 2-deep unroll: 8 edges in flight per wave.
// Lane q of a group owns channels (2q, 2q+1) as ushort2 (4B) loads.
// ---------------------------------------------------------------------------
__global__ __launch_bounds__(256) void layer1_fused(
    const float* __restrict__ x, const bfraw* __restrict__ xb,
    const int* __restrict__ row_ptr, const int* __restrict__ sorted_src,
    const float* __restrict__ w_l, const float* __restrict__ b_l,
    const float* __restrict__ w_r, bfraw* __restrict__ h1b) {
  __shared__ float s_wl[HID * 33];
  __shared__ float s_wr[HID * 33];
  __shared__ float s_mean[4][IN_DIM];
  __shared__ float s_x[4][IN_DIM];

  int tid = threadIdx.x;
  for (int idx = tid; idx < HID * IN_DIM; idx += 256) {
    int j = idx >> 5, f = idx & 31;
    s_wl[j * 33 + f] = w_l[idx];
    s_wr[j * 33 + f] = w_r[idx];
  }
  int w = tid >> 6, lane = tid & 63;
  int node = blockIdx.x * 4 + w;  // exact: 25000*4
  int q = lane & 15, group = lane >> 4;
  int rs = row_ptr[node], re = row_ptr[node + 1];
  int deg = re - rs;
  if (lane >= 32) s_x[w][lane - 32] = x[node * IN_DIM + (lane - 32)];

  float2 a0 = {0.f, 0.f}, a1 = {0.f, 0.f};
  int kk = group;
  for (; kk + 4 < deg; kk += 8) {
    int s0 = sorted_src[rs + kk];
    int s1 = sorted_src[rs + kk + 4];
    ushort2 u0 = *(const ushort2*)&xb[s0 * IN_DIM + 2 * q];
    ushort2 u1 = *(const ushort2*)&xb[s1 * IN_DIM + 2 * q];
    a0.x += bf2f(u0.x); a0.y += bf2f(u0.y);
    a1.x += bf2f(u1.x); a1.y += bf2f(u1.y);
  }
  if (kk < deg) {
    int s0 = sorted_src[rs + kk];
    ushort2 u0 = *(const ushort2*)&xb[s0 * IN_DIM + 2 * q];
    a0.x += bf2f(u0.x); a0.y += bf2f(u0.y);
  }
  a0.x += a1.x; a0.y += a1.y;
  a0.x += __shfl_xor(a0.x, 16, 64); a0.y += __shfl_xor(a0.y, 16, 64);
  a0.x += __shfl_xor(a0.x, 32, 64); a0.y += __shfl_xor(a0.y, 32, 64);
  float rinv = 1.0f / fmaxf((float)deg, 1.0f);
  if (lane < 16) {
    s_mean[w][2 * q]     = a0.x * rinv;
    s_mean[w][2 * q + 1] = a0.y * rinv;
  }
  __syncthreads();

  int j = lane;
  float acc = b_l[j];
#pragma unroll
  for (int ff = 0; ff < IN_DIM; ++ff)
    acc += s_mean[w][ff] * s_wl[j * 33 + ff] + s_x[w][ff] * s_wr[j * 33 + ff];
  h1b[node * HID + j] = f2bf(fmaxf(acc, 0.0f));
}

// ---------------------------------------------------------------------------
// Layer 2 fused: gather-mean(bf16 h1) + lin_l + lin_r + relu + classifier.
// 2 half-wave groups/wave, 2-deep unroll: 4 edges in flight per wave.
// Weights in LDS as packed bf16 pairs (19.2 KB total -> 8 blocks/CU).
// ---------------------------------------------------------------------------
__global__ __launch_bounds__(256) void layer2_fused(
    const bfraw* __restrict__ h1b, const int* __restrict__ row_ptr,
    const int* __restrict__ sorted_src, const float* __restrict__ w_l,
    const float* __restrict__ b_l, const float* __restrict__ w_r,
    const float* __restrict__ wc, const float* __restrict__ bc,
    float* __restrict__ out) {
  __shared__ ushort2 s_wl[HID * 33];   // [64][33] pairs, (j+p)%32 banks -> free
  __shared__ ushort2 s_wr[HID * 33];
  __shared__ float s_mean[4][HID];
  __shared__ float s_h[4][HID];
  __shared__ float s_wc[HID];

  int tid = threadIdx.x;
  for (int idx = tid; idx < HID * HID / 2; idx += 256) {
    int j = idx >> 5;   // row 0..63
    int p = idx & 31;   // pair 0..31
    float2 vl = *(const float2*)&w_l[j * HID + 2 * p];
    float2 vr = *(const float2*)&w_r[j * HID + 2 * p];
    s_wl[j * 33 + p] = make_ushort2(f2bf(vl.x), f2bf(vl.y));
    s_wr[j * 33 + p] = make_ushort2(f2bf(vr.x), f2bf(vr.y));
  }
  if (tid < HID) s_wc[tid] = wc[tid];

  int w = tid >> 6, lane = tid & 63;
  int node = blockIdx.x * 4 + w;
  int l = lane & 31, half = lane >> 5;
  int rs = row_ptr[node], re = row_ptr[node + 1];
  int deg = re - rs;
  s_h[w][lane] = bf2f(h1b[node * HID + lane]);

  float2 a0 = {0.f, 0.f}, a1 = {0.f, 0.f};
  int kk = half;
  for (; kk + 2 < deg; kk += 4) {
    int s0 = sorted_src[rs + kk];
    int s1 = sorted_src[rs + kk + 2];
    ushort2 u0 = *(const ushort2*)&h1b[s0 * HID + 2 * l];
    ushort2 u1 = *(const ushort2*)&h1b[s1 * HID + 2 * l];
    a0.x += bf2f(u0.x); a0.y += bf2f(u0.y);
    a1.x += bf2f(u1.x); a1.y += bf2f(u1.y);
  }
  if (kk < deg) {
    int s0 = sorted_src[rs + kk];
    ushort2 u0 = *(const ushort2*)&h1b[s0 * HID + 2 * l];
    a0.x += bf2f(u0.x); a0.y += bf2f(u0.y);
  }
  a0.x += a1.x; a0.y += a1.y;
  a0.x += __shfl_xor(a0.x, 32, 64);
  a0.y += __shfl_xor(a0.y, 32, 64);
  float rinv = 1.0f / fmaxf((float)deg, 1.0f);
  if (half == 0) {
    s_mean[w][2 * l]     = a0.x * rinv;
    s_mean[w][2 * l + 1] = a0.y * rinv;
  }
  __syncthreads();

  int j = lane;
  float acc = b_l[j];
#pragma unroll
  for (int p = 0; p < HID / 2; ++p) {
    ushort2 wl = s_wl[j * 33 + p];
    ushort2 wr = s_wr[j * 33 + p];
    acc += s_mean[w][2 * p] * bf2f(wl.x) + s_mean[w][2 * p + 1] * bf2f(wl.y)
         + s_h[w][2 * p]   * bf2f(wr.x) + s_h[w][2 * p + 1]   * bf2f(wr.y);
  }
  float h2 = fmaxf(acc, 0.f);
  float contrib = h2 * s_wc[j];
#pragma unroll
  for (int off = 32; off > 0; off >>= 1)
    contrib += __shfl_down(contrib, off, 64);
  if (lane == 0) out[node] = contrib + bc[0];
}

// ---------------------------------------------------------------------------
extern "C" void kernel_launch(void* const* d_in, const int* in_sizes, int n_in,
                              void* d_out, int out_size, void* d_ws, size_t ws_size,
                              hipStream_t stream) {
  const float* x   = (const float*)d_in[0];
  const int*   ei  = (const int*)d_in[1];
  const float* w1l = (const float*)d_in[2];
  const float* b1l = (const float*)d_in[3];
  const float* w1r = (const float*)d_in[4];
  const float* w2l = (const float*)d_in[5];
  const float* b2l = (const float*)d_in[6];
  const float* w2r = (const float*)d_in[7];
  const float* wc  = (const float*)d_in[8];
  const float* bc  = (const float*)d_in[9];
  float* out = (float*)d_out;

  const int* src = ei;             // edge_index[0]
  const int* dst = ei + N_EDGES;   // edge_index[1]

  // workspace layout (4B-aligned slices)
  char* ws = (char*)d_ws;
  int*   row_ptr    = (int*)(ws + 0);          // 400,004 B
  int*   hist       = (int*)(ws + 400128);     // 400,000 B (reused as cursor)
  int*   blk_sums   = (int*)(ws + 800256);     // 512 B
  int*   sorted_src = (int*)(ws + 800768);     // 12.8 MB
  bfraw* xb         = (bfraw*)(ws + 13600768); // 6.4 MB
  bfraw* h1b        = (bfraw*)(ws + 20000768); // 12.8 MB
  // total 32.8 MB

  hipMemsetAsync(hist, 0, (size_t)N_NODES * sizeof(int), stream);
  to_bf16<<<(N_NODES * IN_DIM + 255) / 256, 256, 0, stream>>>(x, xb,
                                                              N_NODES * IN_DIM);
  hist_kernel<<<(N_EDGES + 255) / 256, 256, 0, stream>>>(dst, hist);
  scan_local<<<N_SCAN_BLOCKS, 256, 0, stream>>>(hist, row_ptr, blk_sums);
  scan_blk<<<1, 128, 0, stream>>>(blk_sums);
  scan_add<<<N_SCAN_BLOCKS, 256, 0, stream>>>(row_ptr, blk_sums);
  hipMemsetAsync(hist, 0, (size_t)N_NODES * sizeof(int), stream);  // -> cursor
  fill_kernel<<<(N_EDGES + 255) / 256, 256, 0, stream>>>(src, dst, row_ptr,
                                                         hist, sorted_src);
  layer1_fused<<<N_NODES / 4, 256, 0, stream>>>(x, xb, row_ptr, sorted_src,
                                                w1l, b1l, w1r, h1b);
  layer2_fused<<<N_NODES / 4, 256, 0, stream>>>(h1b, row_ptr, sorted_src,
                                                w2l, b2l, w2r, wc, bc, out);
}